// Round 2
// 91.079 us; speedup vs baseline: 1.0927x; 1.0927x over previous
//
#include <hip/hip_runtime.h>
#include <math.h>

// Chamfer distance, N=16384 points per cloud (8*2048), 3-D fp32.
// Single-pass: compute each pair (i from pc1, j from pc2) ONCE.
//   v(i,j) = h_i + c_j - dot(p_i, q_j)   (= d2/2),  h=0.5||p||^2, c=0.5||q||^2
// row-min over j  -> dist2 (pc1 -> pc2), register-accumulated per thread
// col-min over i  -> dist1 (pc2 -> pc1), per-chunk partial over IP rows,
//                    flushed via rotation-staggered LDS atomicMin (lane-distinct)
// Init via kernel (NOT hipMemsetAsync): keeps kernel_launch graph-capture-safe.
#define N_PTS 16384
#define TPB   256
#define IP    8                      // rows per thread (register-resident)
#define ROWS_B (TPB * IP)            // 2048 rows per block
#define IBLK  (N_PTS / ROWS_B)       // 8 i-blocks
#define JT    128                    // cols per block (LDS tile, 2 KB)
#define JS    (N_PTS / JT)           // 128 j-blocks  -> grid 1024
#define NCH   (JT / 2)               // 64 chunk positions (2 cols per chunk)
#define REDB  64

__global__ __launch_bounds__(TPB) void chamfer_init(
    unsigned int* __restrict__ dmin, float* __restrict__ outp) {
  int id = blockIdx.x * TPB + threadIdx.x;          // 0 .. 2*N_PTS-1
  dmin[id] = 0x7F800000u;  // +inf bits (d2 >= 0, so uint order == float order)
  if (id == 0) outp[0] = 0.f;        // harness poisons d_out with 0xAA
}

__global__ __launch_bounds__(TPB, 4) void chamfer_min(
    const float* __restrict__ p1, const float* __restrict__ p2,
    unsigned int* __restrict__ dmin) {
  __shared__ float4 tile[JT];          // pc2 points: (x,y,z, c=0.5||q||^2)
  __shared__ unsigned int cmin[JT];    // per-block col-min partials (uint bits)

  const int jbase = blockIdx.x * JT;
  for (int t = threadIdx.x; t < JT; t += TPB) {
    float x = p2[3 * (jbase + t) + 0];
    float y = p2[3 * (jbase + t) + 1];
    float z = p2[3 * (jbase + t) + 2];
    tile[t] = make_float4(x, y, z, 0.5f * (x * x + y * y + z * z));
    cmin[t] = 0x7F800000u;             // +inf bits
  }

  // This thread's 8 rows (coalesced: consecutive tx -> consecutive rows).
  const int ibase = blockIdx.y * ROWS_B;
  float nx[IP], ny[IP], nz[IP], h[IP], rmin[IP];
#pragma unroll
  for (int m = 0; m < IP; ++m) {
    int r = ibase + m * TPB + threadIdx.x;
    float x = p1[3 * r + 0], y = p1[3 * r + 1], z = p1[3 * r + 2];
    nx[m] = -x; ny[m] = -y; nz[m] = -z;
    h[m] = 0.5f * (x * x + y * y + z * z);
    rmin[m] = INFINITY;
  }
  __syncthreads();

  // Rotation: lane-distinct chunk positions within a wave (conflict-free LDS
  // reads at 16B stride AND conflict-free lane-distinct LDS atomics); waves
  // staggered by 16 so atomic bursts hit different cols.
  const int base = (threadIdx.x & 63) + ((threadIdx.x >> 6) << 4);
#pragma unroll 2
  for (int s = 0; s < NCH; ++s) {
    const int pos = (base + s) & (NCH - 1);
    float4 qa = tile[pos];             // col j = jbase + pos
    float4 qb = tile[pos + NCH];       // col j = jbase + pos + 64
    float cpa = INFINITY, cpb = INFINITY;
#pragma unroll
    for (int m = 0; m < IP; m += 2) {
      float ta = h[m] + qa.w;
      ta = fmaf(nx[m], qa.x, ta); ta = fmaf(ny[m], qa.y, ta); ta = fmaf(nz[m], qa.z, ta);
      float tb = h[m] + qb.w;
      tb = fmaf(nx[m], qb.x, tb); tb = fmaf(ny[m], qb.y, tb); tb = fmaf(nz[m], qb.z, tb);
      float ua = h[m + 1] + qa.w;
      ua = fmaf(nx[m + 1], qa.x, ua); ua = fmaf(ny[m + 1], qa.y, ua); ua = fmaf(nz[m + 1], qa.z, ua);
      float ub = h[m + 1] + qb.w;
      ub = fmaf(nx[m + 1], qb.x, ub); ub = fmaf(ny[m + 1], qb.y, ub); ub = fmaf(nz[m + 1], qb.z, ub);
      // rows: min3(rmin, col-a, col-b); cols: min3(cp, row-m, row-m+1).
      // Forced v_min3 (data NaN-free; IEEE fminf would bloat 2x).
      asm("v_min3_f32 %0, %1, %2, %3" : "=v"(rmin[m])     : "v"(ta), "v"(tb), "v"(rmin[m]));
      asm("v_min3_f32 %0, %1, %2, %3" : "=v"(rmin[m + 1]) : "v"(ua), "v"(ub), "v"(rmin[m + 1]));
      asm("v_min3_f32 %0, %1, %2, %3" : "=v"(cpa)         : "v"(ta), "v"(ua), "v"(cpa));
      asm("v_min3_f32 %0, %1, %2, %3" : "=v"(cpb)         : "v"(tb), "v"(ub), "v"(cpb));
    }
    // clamp >=0 so uint-bit ordering is monotone, then lane-distinct LDS atomics
    atomicMin(&cmin[pos],       __float_as_uint(fmaxf(cpa, 0.f)));
    atomicMin(&cmin[pos + NCH], __float_as_uint(fmaxf(cpb, 0.f)));
  }

  // Row flush: d2 = 2*max(0, v); rows live at dmin[0..N)
#pragma unroll
  for (int m = 0; m < IP; ++m) {
    float d2 = fmaxf(0.f, 2.f * rmin[m]);
    atomicMin(&dmin[ibase + m * TPB + threadIdx.x], __float_as_uint(d2));
  }

  // Col flush: cols live at dmin[N..2N)
  __syncthreads();
  for (int t = threadIdx.x; t < JT; t += TPB) {
    float v = __uint_as_float(cmin[t]);           // >= 0 (clamped candidates)
    atomicMin(&dmin[N_PTS + jbase + t], __float_as_uint(2.f * v));
  }
}

__global__ __launch_bounds__(TPB) void chamfer_reduce(
    const unsigned int* __restrict__ dmin, float* __restrict__ outp) {
  float s = 0.f;
  for (int i = blockIdx.x * TPB + threadIdx.x; i < 2 * N_PTS; i += REDB * TPB)
    s += sqrtf(__uint_as_float(dmin[i]));
#pragma unroll
  for (int off = 32; off > 0; off >>= 1)
    s += __shfl_down(s, off, 64);
  __shared__ float partial[TPB / 64];
  if ((threadIdx.x & 63) == 0) partial[threadIdx.x >> 6] = s;
  __syncthreads();
  if (threadIdx.x == 0) {
    float t = 0.f;
    for (int w = 0; w < TPB / 64; ++w) t += partial[w];
    // mean(dist1) + mean(dist2) = (sum of all 2N nn-distances) / N
    atomicAdd(outp, t * (1.0f / (float)N_PTS));
  }
}

extern "C" void kernel_launch(void* const* d_in, const int* in_sizes, int n_in,
                              void* d_out, int out_size, void* d_ws, size_t ws_size,
                              hipStream_t stream) {
  const float* pc1 = (const float*)d_in[0];
  const float* pc2 = (const float*)d_in[1];
  unsigned int* dmin = (unsigned int*)d_ws;       // 2N uint = 128 KB

  chamfer_init<<<(2 * N_PTS) / TPB, TPB, 0, stream>>>(dmin, (float*)d_out);
  chamfer_min<<<dim3(JS, IBLK), TPB, 0, stream>>>(pc1, pc2, dmin);
  chamfer_reduce<<<REDB, TPB, 0, stream>>>(dmin, (float*)d_out);
}